// Round 18
// baseline (111.175 us; speedup 1.0000x reference)
//
#include <hip/hip_runtime.h>
#include <stdint.h>
#include <stddef.h>

// MultiHeadAttention: B=2, S=2048, D=1024, H=16, Dh=64
// Round 18:
//   cvt6 : unchanged
//   proj3: fused-N GEMM (M=4096 x N=3072) at 128x128 tile -> 768 blocks
//          (full CU coverage, 2/CU), 4 waves 2Mx2N, BK=64 dbuf, R17's
//          quad-read-ahead deep-phase (1 barrier/K-tile), XCD-chunked
//          block swizzle (each XCD owns 4 A-panels).
//   attn : R10 exact (register-P, ones-MFMA l, full unroll, raw exp2).

#define NH  16
#define DH  64
#define SEQ 2048
#define DM  1024
#define NB  2

#define ACT_N (NB * SEQ * DM)
#define W_N   (DM * DM)
#define QSCALE 0.18033688011116012f   // log2(e)/sqrt(64)

typedef float  f32x4  __attribute__((ext_vector_type(4)));
typedef __bf16 bf16x8 __attribute__((ext_vector_type(8)));
typedef __bf16 bf16x4 __attribute__((ext_vector_type(4)));

__device__ __forceinline__ __bf16 f2bf(float f) { return (__bf16)f; }

__device__ __forceinline__ float fexp2(float x) {
    float r; asm("v_exp_f32 %0, %1" : "=v"(r) : "v"(x)); return r;
}

__device__ __forceinline__ void gload_lds16(const void* g, void* l) {
    __builtin_amdgcn_global_load_lds(
        (const __attribute__((address_space(1))) void*)g,
        (__attribute__((address_space(3))) void*)l, 16, 0, 0);
}

// ---------------------------------------------------------------------------
__global__ __launch_bounds__(256) void cvt6(
    const float* __restrict__ s0, const float* __restrict__ s1,
    const float* __restrict__ s2, const float* __restrict__ s3,
    const float* __restrict__ s4, const float* __restrict__ s5,
    __bf16* __restrict__ d0, __bf16* __restrict__ d1, __bf16* __restrict__ d2,
    __bf16* __restrict__ d3, __bf16* __restrict__ d4, __bf16* __restrict__ d5)
{
    const float* s; __bf16* d; int n;
    switch (blockIdx.z) {
        case 0: s = s0; d = d0; n = ACT_N; break;
        case 1: s = s1; d = d1; n = ACT_N; break;
        case 2: s = s2; d = d2; n = ACT_N; break;
        case 3: s = s3; d = d3; n = W_N;   break;
        case 4: s = s4; d = d4; n = W_N;   break;
        default: s = s5; d = d5; n = W_N;  break;
    }
    const size_t i = ((size_t)blockIdx.x * 256 + threadIdx.x) * 8;
    if (i >= (size_t)n) return;
    float4 f0 = *(const float4*)(s + i);
    float4 f1 = *(const float4*)(s + i + 4);
    bf16x8 o;
    o[0] = f2bf(f0.x); o[1] = f2bf(f0.y); o[2] = f2bf(f0.z); o[3] = f2bf(f0.w);
    o[4] = f2bf(f1.x); o[5] = f2bf(f1.y); o[6] = f2bf(f1.z); o[7] = f2bf(f1.w);
    *(bf16x8*)(d + i) = o;
}

// ---------------------------------------------------------------------------
// proj3: fused QKV NT GEMM, 128x128 tile, BK=64, 4 waves (2Mx2N), dbuf,
// quad-read-ahead deep-phase. 768 blocks, XCD-chunked swizzle.
// LDS [128 rows][64 cols bf16]; chunk c of row r at phys c ^ (r&7).
// Q/K output [bh][s][dh] (swapped mfma, Q scaled); V output [bh][dh][s].
// ---------------------------------------------------------------------------
__global__ __launch_bounds__(256) void proj3(
    const __bf16* __restrict__ Xq, const __bf16* __restrict__ Xk, const __bf16* __restrict__ Xv,
    const __bf16* __restrict__ Wq, const __bf16* __restrict__ Wk, const __bf16* __restrict__ Wv,
    const float* __restrict__ bq, const float* __restrict__ bk, const float* __restrict__ bv,
    __bf16* __restrict__ dq, __bf16* __restrict__ dk, __bf16* __restrict__ dv)
{
    __shared__ __align__(16) __bf16 sA[2][8192];   // 16 KB/slot: 128 x 64
    __shared__ __align__(16) __bf16 sB[2][8192];   // total 64 KB

    // XCD-chunked bijective swizzle: 768 = 8 XCDs x 96. Each XCD gets
    // j in [xcd*96, +96) -> 4 consecutive A-panels (mb) x 24 nb.
    const int li   = blockIdx.x;
    const int j    = (li & 7) * 96 + (li >> 3);
    const int mb   = (j / 24) * 128;
    const int nbg  = (j % 24) * 128;        // global col in [0, 3072)
    const int tensor = nbg >> 10;
    const int nb   = nbg & 1023;            // col within tensor

    const __bf16 *X, *W; const float* bias; __bf16* dst;
    if (tensor == 0)      { X = Xq; W = Wq; bias = bq; dst = dq; }
    else if (tensor == 1) { X = Xk; W = Wk; bias = bk; dst = dk; }
    else                  { X = Xv; W = Wv; bias = bv; dst = dv; }
    const bool vpath = (tensor == 2);

    const int lane = threadIdx.x & 63;
    const int wv   = threadIdx.x >> 6;      // 0..3
    const int lm0  = (wv >> 1) * 64;        // wave M offset
    const int ln0  = (wv & 1) * 64;         // wave N offset
    const int lr = lane & 15;
    const int lg = lane >> 4;

    // staging: wave wv covers tile rows [wv*32, +32) of A and B.
    const int srow = lane >> 3;             // 0..7
    const int gch  = (lane & 7) ^ srow;
    const __bf16* xs = X + (size_t)(mb + wv * 32 + srow) * DM + gch * 8;
    const __bf16* ws = W + (size_t)(nb + wv * 32 + srow) * DM + gch * 8;

#define LA(BUF, T, I) gload_lds16(xs + (size_t)(T) * 64 + (size_t)(I) * 8 * DM, \
                                  &sA[BUF][(wv * 32 + (I) * 8) * 64])
#define LB(BUF, T, I) gload_lds16(ws + (size_t)(T) * 64 + (size_t)(I) * 8 * DM, \
                                  &sB[BUF][(wv * 32 + (I) * 8) * 64])

    const int rsw  = (lr & 7) << 4;
    const int rdk0 = (0 * 64 + lg * 16) ^ rsw;
    const int rdk1 = (1 * 64 + lg * 16) ^ rsw;
    const int arow = (lm0 + lr) * 128;      // byte offset of A frag row
    const int brow = (ln0 + lr) * 128;

    f32x4 acc[16];
#pragma unroll
    for (int i = 0; i < 16; ++i) acc[i] = (f32x4){0.f, 0.f, 0.f, 0.f};

    bf16x8 aP[4], bP[4], aQ2[4], bQ2[4];

#define RDA(R, CA, KS) { \
    _Pragma("unroll") for (int mt = 0; mt < 4; ++mt) \
        R[mt] = *(const bf16x8*)((CA) + arow + mt * 16 * 128 + ((KS) ? rdk1 : rdk0)); }
#define RDB(R, CB, KS) { \
    _Pragma("unroll") for (int nt = 0; nt < 4; ++nt) \
        R[nt] = *(const bf16x8*)((CB) + brow + nt * 16 * 128 + ((KS) ? rdk1 : rdk0)); }

#define MFMAQ(AA, BB) { \
    __builtin_amdgcn_s_setprio(1); \
    if (!vpath) { \
        _Pragma("unroll") for (int nt = 0; nt < 4; ++nt) \
        _Pragma("unroll") for (int mt = 0; mt < 4; ++mt) \
            acc[nt * 4 + mt] = __builtin_amdgcn_mfma_f32_16x16x32_bf16( \
                BB[nt], AA[mt], acc[nt * 4 + mt], 0, 0, 0); \
    } else { \
        _Pragma("unroll") for (int mt = 0; mt < 4; ++mt) \
        _Pragma("unroll") for (int nt = 0; nt < 4; ++nt) \
            acc[mt * 4 + nt] = __builtin_amdgcn_mfma_f32_16x16x32_bf16( \
                AA[mt], BB[nt], acc[mt * 4 + nt], 0, 0, 0); } \
    __builtin_amdgcn_s_setprio(0); }

    // prologue
#pragma unroll
    for (int i = 0; i < 4; ++i) { LA(0, 0, i); LB(0, 0, i); }
    __syncthreads();
    {
        const char* ca = (const char*)&sA[0][0];
        const char* cb = (const char*)&sB[0][0];
        RDA(aP, ca, 0);
        RDB(bP, cb, 0);
    }

#pragma unroll
    for (int t = 0; t < 16; ++t) {
        const int cur = t & 1, nxt = cur ^ 1;
        const char* ca  = (const char*)&sA[cur][0];
        const char* cb  = (const char*)&sB[cur][0];
        const char* caN = (const char*)&sA[nxt][0];
        const char* cbN = (const char*)&sB[nxt][0];
        const bool more = (t + 1 < 16);

        // phase 0: ks0 MFMA; read ks1 frags; stage first half of next tile
        if (more) { LA(nxt, t + 1, 0); LA(nxt, t + 1, 1); LB(nxt, t + 1, 0); LB(nxt, t + 1, 1); }
        RDA(aQ2, ca, 1);
        RDB(bQ2, cb, 1);
        MFMAQ(aP, bP);

        // phase 1: ks1 MFMA; stage second half; barrier; read next ks0
        if (more) { LA(nxt, t + 1, 2); LA(nxt, t + 1, 3); LB(nxt, t + 1, 2); LB(nxt, t + 1, 3); }
        MFMAQ(aQ2, bQ2);
        if (more) {
            __syncthreads();
            RDA(aP, caN, 0);
            RDB(bP, cbN, 0);
        }
    }
#undef MFMAQ
#undef RDA
#undef RDB
#undef LA
#undef LB

    // ---- epilogue ----
    if (!vpath) {
        // D^T: lane n = nb+ln0+nt*16+lg*4 (+4 dh), m = mb+lm0+mt*16+lr
        const float scale = (tensor == 0) ? QSCALE : 1.0f;
#pragma unroll
        for (int nt = 0; nt < 4; ++nt) {
            const int n_base = nb + ln0 + nt * 16 + lg * 4;
            const float4 bb = *(const float4*)&bias[n_base];
            const int h = n_base >> 6, dh = n_base & 63;
#pragma unroll
            for (int mt = 0; mt < 4; ++mt) {
                const int m_g = mb + lm0 + mt * 16 + lr;
                const int bi = m_g >> 11;
                const int s  = m_g & (SEQ - 1);
                const f32x4 v = acc[nt * 4 + mt];
                bf16x4 w;
                w[0] = f2bf((v[0] + bb.x) * scale);
                w[1] = f2bf((v[1] + bb.y) * scale);
                w[2] = f2bf((v[2] + bb.z) * scale);
                w[3] = f2bf((v[3] + bb.w) * scale);
                *(bf16x4*)&dst[((size_t)((bi * NH + h) * SEQ + s)) * DH + dh] = w;
            }
        }
    } else {
        // D: lane m = mb+lm0+mt*16+lg*4 (+4 s), n = nb+ln0+nt*16+lr
        const int h = (nb + ln0) >> 6;   // 64-aligned wave strip: one head
#pragma unroll
        for (int nt = 0; nt < 4; ++nt) {
            const int n_g = nb + ln0 + nt * 16 + lr;
            const float bb = bias[n_g];
            const int dh = n_g & 63;
#pragma unroll
            for (int mt = 0; mt < 4; ++mt) {
                const int m_g = mb + lm0 + mt * 16 + lg * 4;
                const int bi = m_g >> 11;
                const int s0 = m_g & (SEQ - 1);
                const f32x4 v = acc[mt * 4 + nt];
                bf16x4 w;
#pragma unroll
                for (int r = 0; r < 4; ++r) w[r] = f2bf(v[r] + bb);
                *(bf16x4*)&dst[((size_t)((bi * NH + h) * DH + dh)) * SEQ + s0] = w;
            }
        }
    }
}

// ---------------------------------------------------------------------------
// Unnormalized streaming attention, register P, l via ones-MFMA, FULL UNROLL.
// Per tile: SMAX(t) | barrier | STAGE(t+2) ; QK(t+1) ; PV(t).  (R10 verbatim)
// ---------------------------------------------------------------------------
__global__ __launch_bounds__(256) void attn_kernel(
    const __bf16* __restrict__ qh, const __bf16* __restrict__ kh,
    const __bf16* __restrict__ vT, float* __restrict__ out)
{
    __shared__ __align__(16) __bf16 kbuf[3][4096];   // 24 KB  [key][d] swizzled
    __shared__ __align__(16) __bf16 vbuf[3][4096];   // 24 KB  [d][key] swizzled

    const int tid  = threadIdx.x;
    const int lane = tid & 63;
    const int wv   = tid >> 6;
    const int i    = blockIdx.x;
    const int slot = i >> 3;
    const int bh   = (i & 7) * 4 + (slot >> 4);   // XCD x owns heads 4x..4x+3
    const int qt   = slot & 15;
    const size_t hb = (size_t)bh * SEQ * DH;
    const int q0 = qt * 128 + wv * 32;
    const int lq = lane & 15;
    const int lg = lane >> 4;
    const int swz = (lq & 7) << 4;

    const int p0 = tid, p1 = tid + 256;
    const int c0 = (p0 ^ ((p0 >> 3) & 7)) & 7;
    const int c1 = (p1 ^ ((p1 >> 3) & 7)) & 7;
    const int r0 = p0 >> 3, r1 = p1 >> 3;
    const int gr0 = (r0 & 35) | ((r0 & 12) << 1) | ((r0 & 16) >> 2);  // g(r0)
    const int gr1 = (r1 & 35) | ((r1 & 12) << 1) | ((r1 & 16) >> 2);  // g(r1)
    const __bf16* ks0 = kh + hb + (size_t)gr0 * DH + c0 * 8;
    const __bf16* ks1 = kh + hb + (size_t)gr1 * DH + c1 * 8;
    const __bf16* vs0 = vT + hb + (size_t)r0 * SEQ + c0 * 8;
    const __bf16* vs1 = vT + hb + (size_t)r1 * SEQ + c1 * 8;
    const int dst0 = wv * 512;
    const int dst1 = 2048 + wv * 512;

#define STAGE(SEL, TI) { \
    gload_lds16(ks0 + (size_t)(TI) * 64 * DH, &kbuf[SEL][dst0]); \
    gload_lds16(ks1 + (size_t)(TI) * 64 * DH, &kbuf[SEL][dst1]); \
    gload_lds16(vs0 + (TI) * 64, &vbuf[SEL][dst0]); \
    gload_lds16(vs1 + (TI) * 64, &vbuf[SEL][dst1]); }

    bf16x8 bQ[2][2];
#pragma unroll
    for (int qtf = 0; qtf < 2; ++qtf)
#pragma unroll
        for (int ks = 0; ks < 2; ++ks)
            bQ[qtf][ks] = *(const bf16x8*)(qh + hb +
                (size_t)(q0 + qtf * 16 + lq) * DH + ks * 32 + lg * 8);

    bf16x8 ONES;
#pragma unroll
    for (int e = 0; e < 8; ++e) ONES[e] = f2bf(1.0f);

    f32x4 O[2][4];
#pragma unroll
    for (int qtf = 0; qtf < 2; ++qtf)
#pragma unroll
        for (int dt = 0; dt < 4; ++dt) O[qtf][dt] = (f32x4){0.f, 0.f, 0.f, 0.f};
    f32x4 Ol[2];
    Ol[0] = (f32x4){0.f, 0.f, 0.f, 0.f};
    Ol[1] = (f32x4){0.f, 0.f, 0.f, 0.f};

    const int rdk0 = lq * 128 + ((0 * 64 + lg * 16) ^ swz);
    const int rdk1 = lq * 128 + ((1 * 64 + lg * 16) ^ swz);

    f32x4 scA[2][4], scB[2][4];
    bf16x8 paf[2][2];

#define QK(SL, SC) { \
    const char* kc = (const char*)&kbuf[SL][0]; \
    _Pragma("unroll") for (int kt = 0; kt < 4; ++kt) { \
        const bf16x8 ak0 = *(const bf16x8*)(kc + kt * 2048 + rdk0); \
        const bf16x8 ak1 = *(const bf16x8*)(kc + kt * 2048 + rdk1); \
        _Pragma("unroll") for (int qtf = 0; qtf < 2; ++qtf) { \
            f32x4 c = (f32x4){0.f, 0.f, 0.f, 0.f}; \
            c = __builtin_amdgcn_mfma_f32_16x16x32_bf16(ak0, bQ[qtf][0], c, 0, 0, 0); \
            c = __builtin_amdgcn_mfma_f32_16x16x32_bf16(ak1, bQ[qtf][1], c, 0, 0, 0); \
            SC[qtf][kt] = c; } } }

#define SMAX(SC) { \
    _Pragma("unroll") for (int qtf = 0; qtf < 2; ++qtf) \
    _Pragma("unroll") for (int ks = 0; ks < 2; ++ks) { \
        bf16x8 w; \
        _Pragma("unroll") for (int r = 0; r < 4; ++r) { \
            w[r]     = f2bf(fexp2(SC[qtf][2 * ks][r])); \
            w[4 + r] = f2bf(fexp2(SC[qtf][2 * ks + 1][r])); } \
        paf[qtf][ks] = w; } }

#define PV(SL) { \
    const char* vc = (const char*)&vbuf[SL][0]; \
    _Pragma("unroll") for (int ks = 0; ks < 2; ++ks) { \
        const int rd = (ks == 0) ? rdk0 : rdk1; \
        _Pragma("unroll") for (int dt = 0; dt < 4; ++dt) { \
            const bf16x8 bv = *(const bf16x8*)(vc + dt * 2048 + rd); \
            O[0][dt] = __builtin_amdgcn_mfma_f32_16x16x32_bf16(paf[0][ks], bv, O[0][dt], 0, 0, 0); \
            O[1][dt] = __builtin_amdgcn_mfma_f32_16x16x32_bf16(paf[1][ks], bv, O[1][dt], 0, 0, 0); } \
        Ol[0] = __builtin_amdgcn_mfma_f32_16x16x32_bf16(paf[0][ks], ONES, Ol[0], 0, 0, 0); \
        Ol[1] = __builtin_amdgcn_mfma_f32_16x16x32_bf16(paf[1][ks], ONES, Ol[1], 0, 0, 0); } }

#define BODY(T, SCUR, SNXT) { \
    SMAX(SCUR); \
    __syncthreads(); \
    if ((T) + 2 < 32) STAGE(((T) + 2) % 3, (T) + 2); \
    __builtin_amdgcn_s_setprio(1); \
    if ((T) + 1 < 32) QK(((T) + 1) % 3, SNXT); \
    PV((T) % 3); \
    __builtin_amdgcn_s_setprio(0); }

    STAGE(0, 0);
    STAGE(1, 1);
    __syncthreads();
    QK(0, scA);

#pragma unroll
    for (int t = 0; t < 32; t += 2) {
        BODY(t, scA, scB);
        BODY(t + 1, scB, scA);
    }
#undef BODY
#undef PV
#undef SMAX
#undef QK
#undef STAGE

    const int b = bh >> 4, h = bh & 15;
#pragma unroll
    for (int qtf = 0; qtf < 2; ++qtf) {
#pragma unroll
        for (int r = 0; r < 4; ++r) {
            const float li = 1.0f / (qtf ? Ol[1][r] : Ol[0][r]);
            const int s_g = q0 + qtf * 16 + lg * 4 + r;
            float* op = out + ((size_t)(b * SEQ + s_g)) * DM + h * DH;
#pragma unroll
            for (int dt = 0; dt < 4; ++dt)
                op[dt * 16 + lq] = O[qtf][dt][r] * li;
        }
    }
}

// ---------------------------------------------------------------------------
extern "C" void kernel_launch(void* const* d_in, const int* in_sizes, int n_in,
                              void* d_out, int out_size, void* d_ws, size_t ws_size,
                              hipStream_t stream)
{
    (void)in_sizes; (void)n_in; (void)out_size; (void)ws_size;
    const float* q  = (const float*)d_in[0];
    const float* k  = (const float*)d_in[1];
    const float* v  = (const float*)d_in[2];
    const float* Wq = (const float*)d_in[3];
    const float* bq = (const float*)d_in[4];
    const float* Wk = (const float*)d_in[5];
    const float* bk = (const float*)d_in[6];
    const float* Wv = (const float*)d_in[7];
    const float* bv = (const float*)d_in[8];

    const size_t act = (size_t)ACT_N;
    const size_t wn  = (size_t)W_N;
    __bf16* qx  = (__bf16*)d_ws;
    __bf16* kx  = qx + act;
    __bf16* vx  = kx + act;
    __bf16* wqb = vx + act;
    __bf16* wkb = wqb + wn;
    __bf16* wvb = wkb + wn;
    __bf16* qhd = wvb + wn;
    __bf16* khd = qhd + act;
    __bf16* vhd = khd + act;               // vhd: [bh][64][s] transposed
    float* out = (float*)d_out;

    cvt6<<<dim3(2048, 1, 6), dim3(256), 0, stream>>>(
        q, k, v, Wq, Wk, Wv, qx, kx, vx, wqb, wkb, wvb);
    proj3<<<dim3(768), dim3(256), 0, stream>>>(
        qx, kx, vx, wqb, wkb, wvb, bq, bk, bv, qhd, khd, vhd);
    attn_kernel<<<dim3(512), dim3(256), 0, stream>>>(qhd, khd, vhd, out);
}

// Round 20
// 89.990 us; speedup vs baseline: 1.2354x; 1.2354x over previous
//
#include <hip/hip_runtime.h>
#include <stdint.h>
#include <stddef.h>

// MultiHeadAttention: B=2, S=2048, D=1024, H=16, Dh=64
// Round 20 = Round 17 verbatim (best measured: 90.2 us).
//   cvt6 : fp32->bf16 pre-convert
//   proj3: fused-N (QKV as M=4096 x N=3072) deep-phase GEMM. 256x256 tile,
//          BK=64, 512 thr (8 waves 2Mx4N, 128x64/wave), dbuf 128KB LDS,
//          4 quads/K-tile with ds_read one quad ahead, one __syncthreads
//          per K-tile (64 MFMA between barriers), swizzled LDS.
//   attn : register-P unnormalized attention (permuted-K staging so exp2'd
//          QK fragments ARE the PV A-fragments), l via ones-MFMA, 3-slot
//          pipeline, full unroll, raw v_exp_f32.

#define NH  16
#define DH  64
#define SEQ 2048
#define DM  1024
#define NB  2

#define ACT_N (NB * SEQ * DM)
#define W_N   (DM * DM)
#define QSCALE 0.18033688011116012f   // log2(e)/sqrt(64)

typedef float  f32x4  __attribute__((ext_vector_type(4)));
typedef __bf16 bf16x8 __attribute__((ext_vector_type(8)));
typedef __bf16 bf16x4 __attribute__((ext_vector_type(4)));

__device__ __forceinline__ __bf16 f2bf(float f) { return (__bf16)f; }

__device__ __forceinline__ float fexp2(float x) {
    float r; asm("v_exp_f32 %0, %1" : "=v"(r) : "v"(x)); return r;
}

__device__ __forceinline__ void gload_lds16(const void* g, void* l) {
    __builtin_amdgcn_global_load_lds(
        (const __attribute__((address_space(1))) void*)g,
        (__attribute__((address_space(3))) void*)l, 16, 0, 0);
}

// ---------------------------------------------------------------------------
__global__ __launch_bounds__(256) void cvt6(
    const float* __restrict__ s0, const float* __restrict__ s1,
    const float* __restrict__ s2, const float* __restrict__ s3,
    const float* __restrict__ s4, const float* __restrict__ s5,
    __bf16* __restrict__ d0, __bf16* __restrict__ d1, __bf16* __restrict__ d2,
    __bf16* __restrict__ d3, __bf16* __restrict__ d4, __bf16* __restrict__ d5)
{
    const float* s; __bf16* d; int n;
    switch (blockIdx.z) {
        case 0: s = s0; d = d0; n = ACT_N; break;
        case 1: s = s1; d = d1; n = ACT_N; break;
        case 2: s = s2; d = d2; n = ACT_N; break;
        case 3: s = s3; d = d3; n = W_N;   break;
        case 4: s = s4; d = d4; n = W_N;   break;
        default: s = s5; d = d5; n = W_N;  break;
    }
    const size_t i = ((size_t)blockIdx.x * 256 + threadIdx.x) * 8;
    if (i >= (size_t)n) return;
    float4 f0 = *(const float4*)(s + i);
    float4 f1 = *(const float4*)(s + i + 4);
    bf16x8 o;
    o[0] = f2bf(f0.x); o[1] = f2bf(f0.y); o[2] = f2bf(f0.z); o[3] = f2bf(f0.w);
    o[4] = f2bf(f1.x); o[5] = f2bf(f1.y); o[6] = f2bf(f1.z); o[7] = f2bf(f1.w);
    *(bf16x8*)(d + i) = o;
}

// ---------------------------------------------------------------------------
// proj3: fused QKV NT GEMM, 256x256 tile, BK=64, 8 waves, deep-phase.
// blockIdx.y 0..11: tensor = by>>2 (0 Q, 1 K, 2 V), nb = (by&3)*256.
// LDS: [256 rows][64 cols bf16]; 16B chunk c of row r at phys c ^ (r&7).
// ---------------------------------------------------------------------------
__global__ __launch_bounds__(512) void proj3(
    const __bf16* __restrict__ Xq, const __bf16* __restrict__ Xk, const __bf16* __restrict__ Xv,
    const __bf16* __restrict__ Wq, const __bf16* __restrict__ Wk, const __bf16* __restrict__ Wv,
    const float* __restrict__ bq, const float* __restrict__ bk, const float* __restrict__ bv,
    __bf16* __restrict__ dq, __bf16* __restrict__ dk, __bf16* __restrict__ dv)
{
    __shared__ __align__(16) __bf16 sA[2][16384];   // 32 KB/slot: 256 x 64
    __shared__ __align__(16) __bf16 sB[2][16384];   // total 128 KB

    const int tid  = threadIdx.x;
    const int lane = tid & 63;
    const int wv   = tid >> 6;          // 0..7
    const int wm   = wv >> 2;           // 0..1  (M half: 128 rows)
    const int wn   = wv & 3;            // 0..3  (N quarter: 64 cols)
    const int tensor = blockIdx.y >> 2;
    const int nb   = (blockIdx.y & 3) * 256;
    const int mb   = blockIdx.x * 256;

    const __bf16 *X, *W; const float* bias; __bf16* dst;
    if (tensor == 0)      { X = Xq; W = Wq; bias = bq; dst = dq; }
    else if (tensor == 1) { X = Xk; W = Wk; bias = bk; dst = dk; }
    else                  { X = Xv; W = Wv; bias = bv; dst = dv; }
    const bool vpath = (tensor == 2);

    const int lr = lane & 15;
    const int lg = lane >> 4;

    const int srow = lane >> 3;
    const int gch  = (lane & 7) ^ srow;
    const __bf16* xs = X + (size_t)(mb + wv * 32 + srow) * DM + gch * 8;
    const __bf16* ws = W + (size_t)(nb + wv * 32 + srow) * DM + gch * 8;

#define LA(BUF, T, I) gload_lds16(xs + (size_t)(T) * 64 + (size_t)(I) * 8 * DM, \
                                  &sA[BUF][(wv * 32 + (I) * 8) * 64])
#define LB(BUF, T, I) gload_lds16(ws + (size_t)(T) * 64 + (size_t)(I) * 8 * DM, \
                                  &sB[BUF][(wv * 32 + (I) * 8) * 64])

    const int rsw = (lr & 7) << 4;
    const int rdk0 = (0 * 64 + lg * 16) ^ rsw;
    const int rdk1 = (1 * 64 + lg * 16) ^ rsw;
    const int arow = (wm * 128 + lr) * 128;
    const int brow = (wn * 64 + lr) * 128;

    f32x4 acc[32];
#pragma unroll
    for (int i = 0; i < 32; ++i) acc[i] = (f32x4){0.f, 0.f, 0.f, 0.f};

    bf16x8 aP[4], aQ2[4], bP[4], bQ2[4];

#define RDA(R, CA, MH, KS) { \
    _Pragma("unroll") for (int mt = 0; mt < 4; ++mt) \
        R[mt] = *(const bf16x8*)((CA) + arow + ((MH) * 4 + mt) * 16 * 128 + ((KS) ? rdk1 : rdk0)); }
#define RDB(R, CB, KS) { \
    _Pragma("unroll") for (int nt = 0; nt < 4; ++nt) \
        R[nt] = *(const bf16x8*)((CB) + brow + nt * 16 * 128 + ((KS) ? rdk1 : rdk0)); }

#define MFMAQ(MH, AA, BB) { \
    __builtin_amdgcn_s_setprio(1); \
    if (!vpath) { \
        _Pragma("unroll") for (int nt = 0; nt < 4; ++nt) \
        _Pragma("unroll") for (int mt = 0; mt < 4; ++mt) \
            acc[nt * 8 + (MH) * 4 + mt] = __builtin_amdgcn_mfma_f32_16x16x32_bf16( \
                BB[nt], AA[mt], acc[nt * 8 + (MH) * 4 + mt], 0, 0, 0); \
    } else { \
        _Pragma("unroll") for (int mt = 0; mt < 4; ++mt) \
        _Pragma("unroll") for (int nt = 0; nt < 4; ++nt) \
            acc[((MH) * 4 + mt) * 4 + nt] = __builtin_amdgcn_mfma_f32_16x16x32_bf16( \
                AA[mt], BB[nt], acc[((MH) * 4 + mt) * 4 + nt], 0, 0, 0); } \
    __builtin_amdgcn_s_setprio(0); }

#pragma unroll
    for (int i = 0; i < 4; ++i) { LA(0, 0, i); LB(0, 0, i); }
    __syncthreads();
    {
        const char* ca = (const char*)&sA[0][0];
        const char* cb = (const char*)&sB[0][0];
        RDA(aP, ca, 0, 0);
        RDB(bP, cb, 0);
    }

#pragma unroll
    for (int t = 0; t < 16; ++t) {
        const int cur = t & 1, nxt = cur ^ 1;
        const char* ca = (const char*)&sA[cur][0];
        const char* cb = (const char*)&sB[cur][0];
        const char* caN = (const char*)&sA[nxt][0];
        const char* cbN = (const char*)&sB[nxt][0];
        const bool more = (t + 1 < 16);

        if (more) { LA(nxt, t + 1, 0); LA(nxt, t + 1, 1); LB(nxt, t + 1, 0); }
        RDA(aQ2, ca, 1, 0);
        MFMAQ(0, aP, bP);

        if (more) { LA(nxt, t + 1, 2); LA(nxt, t + 1, 3); LB(nxt, t + 1, 1); }
        RDA(aP, ca, 0, 1);
        RDB(bQ2, cb, 1);
        MFMAQ(1, aQ2, bP);

        if (more) { LB(nxt, t + 1, 2); LB(nxt, t + 1, 3); }
        RDA(aQ2, ca, 1, 1);
        MFMAQ(0, aP, bQ2);

        MFMAQ(1, aQ2, bQ2);
        if (more) {
            __syncthreads();
            RDA(aP, caN, 0, 0);
            RDB(bP, cbN, 0);
        }
    }
#undef MFMAQ
#undef RDA
#undef RDB
#undef LA
#undef LB

    if (!vpath) {
        const float scale = (tensor == 0) ? QSCALE : 1.0f;
#pragma unroll
        for (int nt = 0; nt < 4; ++nt) {
            const int n_base = nb + wn * 64 + nt * 16 + lg * 4;
            const float4 bb = *(const float4*)&bias[n_base];
            const int h = n_base >> 6, dh = n_base & 63;
#pragma unroll
            for (int mt = 0; mt < 8; ++mt) {
                const int m_g = mb + wm * 128 + mt * 16 + lr;
                const int bi = m_g >> 11;
                const int s  = m_g & (SEQ - 1);
                const f32x4 v = acc[nt * 8 + mt];
                bf16x4 w;
                w[0] = f2bf((v[0] + bb.x) * scale);
                w[1] = f2bf((v[1] + bb.y) * scale);
                w[2] = f2bf((v[2] + bb.z) * scale);
                w[3] = f2bf((v[3] + bb.w) * scale);
                *(bf16x4*)&dst[((size_t)((bi * NH + h) * SEQ + s)) * DH + dh] = w;
            }
        }
    } else {
        const int h = (nb + wn * 64) >> 6;
#pragma unroll
        for (int nt = 0; nt < 4; ++nt) {
            const int n_g = nb + wn * 64 + nt * 16 + lr;
            const float bb = bias[n_g];
            const int dh = n_g & 63;
#pragma unroll
            for (int mt = 0; mt < 8; ++mt) {
                const int m_g = mb + wm * 128 + mt * 16 + lg * 4;
                const int bi = m_g >> 11;
                const int s0 = m_g & (SEQ - 1);
                const f32x4 v = acc[mt * 4 + nt];
                bf16x4 w;
#pragma unroll
                for (int r = 0; r < 4; ++r) w[r] = f2bf(v[r] + bb);
                *(bf16x4*)&dst[((size_t)((bi * NH + h) * DH + dh)) * SEQ + s0] = w;
            }
        }
    }
}

// ---------------------------------------------------------------------------
// Unnormalized streaming attention, register P, l via ones-MFMA, FULL UNROLL.
// Per tile: SMAX(t) | barrier | STAGE(t+2) ; QK(t+1) ; PV(t).
// ---------------------------------------------------------------------------
__global__ __launch_bounds__(256) void attn_kernel(
    const __bf16* __restrict__ qh, const __bf16* __restrict__ kh,
    const __bf16* __restrict__ vT, float* __restrict__ out)
{
    __shared__ __align__(16) __bf16 kbuf[3][4096];   // 24 KB  [key][d] swizzled
    __shared__ __align__(16) __bf16 vbuf[3][4096];   // 24 KB  [d][key] swizzled

    const int tid  = threadIdx.x;
    const int lane = tid & 63;
    const int wv   = tid >> 6;
    const int i    = blockIdx.x;
    const int slot = i >> 3;
    const int bh   = (i & 7) * 4 + (slot >> 4);   // XCD x owns heads 4x..4x+3
    const int qt   = slot & 15;
    const size_t hb = (size_t)bh * SEQ * DH;
    const int q0 = qt * 128 + wv * 32;
    const int lq = lane & 15;
    const int lg = lane >> 4;
    const int swz = (lq & 7) << 4;

    const int p0 = tid, p1 = tid + 256;
    const int c0 = (p0 ^ ((p0 >> 3) & 7)) & 7;
    const int c1 = (p1 ^ ((p1 >> 3) & 7)) & 7;
    const int r0 = p0 >> 3, r1 = p1 >> 3;
    const int gr0 = (r0 & 35) | ((r0 & 12) << 1) | ((r0 & 16) >> 2);  // g(r0)
    const int gr1 = (r1 & 35) | ((r1 & 12) << 1) | ((r1 & 16) >> 2);  // g(r1)
    const __bf16* ks0 = kh + hb + (size_t)gr0 * DH + c0 * 8;
    const __bf16* ks1 = kh + hb + (size_t)gr1 * DH + c1 * 8;
    const __bf16* vs0 = vT + hb + (size_t)r0 * SEQ + c0 * 8;
    const __bf16* vs1 = vT + hb + (size_t)r1 * SEQ + c1 * 8;
    const int dst0 = wv * 512;
    const int dst1 = 2048 + wv * 512;

#define STAGE(SEL, TI) { \
    gload_lds16(ks0 + (size_t)(TI) * 64 * DH, &kbuf[SEL][dst0]); \
    gload_lds16(ks1 + (size_t)(TI) * 64 * DH, &kbuf[SEL][dst1]); \
    gload_lds16(vs0 + (TI) * 64, &vbuf[SEL][dst0]); \
    gload_lds16(vs1 + (TI) * 64, &vbuf[SEL][dst1]); }

    bf16x8 bQ[2][2];
#pragma unroll
    for (int qtf = 0; qtf < 2; ++qtf)
#pragma unroll
        for (int ks = 0; ks < 2; ++ks)
            bQ[qtf][ks] = *(const bf16x8*)(qh + hb +
                (size_t)(q0 + qtf * 16 + lq) * DH + ks * 32 + lg * 8);

    bf16x8 ONES;
#pragma unroll
    for (int e = 0; e < 8; ++e) ONES[e] = f2bf(1.0f);

    f32x4 O[2][4];
#pragma unroll
    for (int qtf = 0; qtf < 2; ++qtf)
#pragma unroll
        for (int dt = 0; dt < 4; ++dt) O[qtf][dt] = (f32x4){0.f, 0.f, 0.f, 0.f};
    f32x4 Ol[2];
    Ol[0] = (f32x4){0.f, 0.f, 0.f, 0.f};
    Ol[1] = (f32x4){0.f, 0.f, 0.f, 0.f};

    const int rdk0 = lq * 128 + ((0 * 64 + lg * 16) ^ swz);
    const int rdk1 = lq * 128 + ((1 * 64 + lg * 16) ^ swz);

    f32x4 scA[2][4], scB[2][4];
    bf16x8 paf[2][2];

#define QK(SL, SC) { \
    const char* kc = (const char*)&kbuf[SL][0]; \
    _Pragma("unroll") for (int kt = 0; kt < 4; ++kt) { \
        const bf16x8 ak0 = *(const bf16x8*)(kc + kt * 2048 + rdk0); \
        const bf16x8 ak1 = *(const bf16x8*)(kc + kt * 2048 + rdk1); \
        _Pragma("unroll") for (int qtf = 0; qtf < 2; ++qtf) { \
            f32x4 c = (f32x4){0.f, 0.f, 0.f, 0.f}; \
            c = __builtin_amdgcn_mfma_f32_16x16x32_bf16(ak0, bQ[qtf][0], c, 0, 0, 0); \
            c = __builtin_amdgcn_mfma_f32_16x16x32_bf16(ak1, bQ[qtf][1], c, 0, 0, 0); \
            SC[qtf][kt] = c; } } }

#define SMAX(SC) { \
    _Pragma("unroll") for (int qtf = 0; qtf < 2; ++qtf) \
    _Pragma("unroll") for (int ks = 0; ks < 2; ++ks) { \
        bf16x8 w; \
        _Pragma("unroll") for (int r = 0; r < 4; ++r) { \
            w[r]     = f2bf(fexp2(SC[qtf][2 * ks][r])); \
            w[4 + r] = f2bf(fexp2(SC[qtf][2 * ks + 1][r])); } \
        paf[qtf][ks] = w; } }

#define PV(SL) { \
    const char* vc = (const char*)&vbuf[SL][0]; \
    _Pragma("unroll") for (int ks = 0; ks < 2; ++ks) { \
        const int rd = (ks == 0) ? rdk0 : rdk1; \
        _Pragma("unroll") for (int dt = 0; dt < 4; ++dt) { \
            const bf16x8 bv = *(const bf16x8*)(vc + dt * 2048 + rd); \
            O[0][dt] = __builtin_amdgcn_mfma_f32_16x16x32_bf16(paf[0][ks], bv, O[0][dt], 0, 0, 0); \
            O[1][dt] = __builtin_amdgcn_mfma_f32_16x16x32_bf16(paf[1][ks], bv, O[1][dt], 0, 0, 0); } \
        Ol[0] = __builtin_amdgcn_mfma_f32_16x16x32_bf16(paf[0][ks], ONES, Ol[0], 0, 0, 0); \
        Ol[1] = __builtin_amdgcn_mfma_f32_16x16x32_bf16(paf[1][ks], ONES, Ol[1], 0, 0, 0); } }

#define BODY(T, SCUR, SNXT) { \
    SMAX(SCUR); \
    __syncthreads(); \
    if ((T) + 2 < 32) STAGE(((T) + 2) % 3, (T) + 2); \
    __builtin_amdgcn_s_setprio(1); \
    if ((T) + 1 < 32) QK(((T) + 1) % 3, SNXT); \
    PV((T) % 3); \
    __builtin_amdgcn_s_setprio(0); }

    STAGE(0, 0);
    STAGE(1, 1);
    __syncthreads();
    QK(0, scA);

#pragma unroll
    for (int t = 0; t < 32; t += 2) {
        BODY(t, scA, scB);
        BODY(t + 1, scB, scA);
    }
#undef BODY
#undef PV
#undef SMAX
#undef QK
#undef STAGE

    const int b = bh >> 4, h = bh & 15;
#pragma unroll
    for (int qtf = 0; qtf < 2; ++qtf) {
#pragma unroll
        for (int r = 0; r < 4; ++r) {
            const float li = 1.0f / (qtf ? Ol[1][r] : Ol[0][r]);
            const int s_g = q0 + qtf * 16 + lg * 4 + r;
            float* op = out + ((size_t)(b * SEQ + s_g)) * DM + h * DH;
#pragma unroll
            for (int dt = 0; dt < 4; ++dt)
                op[dt * 16 + lq] = O[qtf][dt][r] * li;
        }
    }
}

// ---------------------------------------------------------------------------
extern "C" void kernel_launch(void* const* d_in, const int* in_sizes, int n_in,
                              void* d_out, int out_size, void* d_ws, size_t ws_size,
                              hipStream_t stream)
{
    (void)in_sizes; (void)n_in; (void)out_size; (void)ws_size;
    const float* q  = (const float*)d_in[0];
    const float* k  = (const float*)d_in[1];
    const float* v  = (const float*)d_in[2];
    const float* Wq = (const float*)d_in[3];
    const float* bq = (const float*)d_in[4];
    const float* Wk = (const float*)d_in[5];
    const float* bk = (const float*)d_in[6];
    const float* Wv = (const float*)d_in[7];
    const float* bv = (const float*)d_in[8];

    const size_t act = (size_t)ACT_N;
    const size_t wn  = (size_t)W_N;
    __bf16* qx  = (__bf16*)d_ws;
    __bf16* kx  = qx + act;
    __bf16* vx  = kx + act;
    __bf16* wqb = vx + act;
    __bf16* wkb = wqb + wn;
    __bf16* wvb = wkb + wn;
    __bf16* qhd = wvb + wn;
    __bf16* khd = qhd + act;
    __bf16* vhd = khd + act;               // vhd: [bh][64][s] transposed
    float* out = (float*)d_out;

    cvt6<<<dim3(2048, 1, 6), dim3(256), 0, stream>>>(
        q, k, v, Wq, Wk, Wv, qx, kx, vx, wqb, wkb, wvb);
    proj3<<<dim3(16, 12), dim3(512), 0, stream>>>(
        qx, kx, vx, wqb, wkb, wvb, bq, bk, bv, qhd, khd, vhd);
    attn_kernel<<<dim3(512), dim3(256), 0, stream>>>(qhd, khd, vhd, out);
}